// Round 3
// baseline (414.133 us; speedup 1.0000x reference)
//
#include <hip/hip_runtime.h>
#include <stdint.h>

// ---------------------------------------------------------------------------
// BailingMoE block: T=1024, H=1024, E=16, top-4, I=512 routed, Is=1024 shared
// R10: kill pack_all. Phases read fp32 weights directly: B staged as fp32
// via regs -> LDS [32][132] tile (col XOR-swizzle by k>>3), transpose-read
// 32x ds_read_b32 + round-half-up pack to bf16 frags. A stays glds16 (bf16),
// 2-buffer. One barrier/step, vmcnt(4) keeps next B-stage in flight.
// Saves pack's 171MB/iter HBM round-trip; weights become L3-resident.
// z=0 = shared expert (longest blocks first).
// ---------------------------------------------------------------------------

typedef __attribute__((ext_vector_type(8))) unsigned short ushort8;
typedef __attribute__((ext_vector_type(4))) float f32x4;
typedef __attribute__((ext_vector_type(8))) __bf16 bf16x8;

#define T_TOK 1024
#define HID   1024
#define NEXP  16
#define TOPK  4
#define MINTER 512
#define SINTER 1024

constexpr size_t OFF_COUNTS = 0;
constexpr size_t OFF_LIST   = 1024;
constexpr size_t OFF_WT     = OFF_LIST  + 65536;
constexpr size_t OFF_TIDX   = OFF_WT    + 65536;
constexpr size_t OFF_XB     = OFF_TIDX  + 65536;               // bf16 [1024][1024]
constexpr size_t OFF_HR     = OFF_XB    + 2097152;             // bf16 [16][4096][32]
constexpr size_t OFF_HS     = OFF_HR    + 4194304;             // bf16 [32][1024][32]
constexpr size_t OFF_ROUT   = OFF_HS    + 2097152;             // bf16 [4096][1024]

__device__ __forceinline__ unsigned short f2bf(float f) {
  union { float f; uint32_t u; } v; v.f = f;
  uint32_t r = (v.u + 0x7FFFu + ((v.u >> 16) & 1u)) >> 16;
  return (unsigned short)r;
}
__device__ __forceinline__ float bfu2f(uint32_t u) {
  union { uint32_t u; float f; } v; v.u = u << 16; return v.f;
}
__device__ __forceinline__ bf16x8 as_bf16x8(ushort8 s) {
  union { ushort8 s; bf16x8 b; } u; u.s = s; return u.b;
}
// round-half-up fp32->bf16, two at a time packed into one u32 (lo in low16)
__device__ __forceinline__ uint32_t pk2(float hi, float lo) {
  union { float f; uint32_t u; } a, b; a.f = hi; b.f = lo;
  return ((a.u + 0x8000u) & 0xFFFF0000u) | ((b.u + 0x8000u) >> 16);
}
__device__ __forceinline__ float silu(float g) { return g / (1.f + __expf(-g)); }

__device__ __forceinline__ void glds16(const unsigned short* g, unsigned short* l) {
  __builtin_amdgcn_global_load_lds(
      (const __attribute__((address_space(1))) unsigned int*)g,
      (__attribute__((address_space(3))) unsigned int*)l, 16, 0, 0);
}

#define WAIT_VM4() asm volatile("s_waitcnt vmcnt(4)" ::: "memory")
#define WAIT_VM0() asm volatile("s_waitcnt vmcnt(0)" ::: "memory")
#define BAR_LGKM() asm volatile("s_waitcnt lgkmcnt(0)\ns_barrier" ::: "memory")

// -------------------------- init: zero expert counts -----------------------
__global__ void init_kernel(int* counts) {
  if (threadIdx.x < NEXP) counts[threadIdx.x] = 0;
}

// ------------- router (fp32, one wave/token) + fused x->bf16 write ---------
__global__ __launch_bounds__(64) void router_kernel(
    const float* __restrict__ x, const float* __restrict__ rw,
    int* counts, int* list, float* wt, int* tIdx,
    unsigned short* __restrict__ Xb) {
  const int t = blockIdx.x, l = threadIdx.x;
  float xv[16];
#pragma unroll
  for (int j = 0; j < 16; j++) xv[j] = x[t * HID + j * 64 + l];
#pragma unroll
  for (int j = 0; j < 16; j++) Xb[t * HID + j * 64 + l] = f2bf(xv[j]);
  float p[NEXP];
#pragma unroll
  for (int e = 0; e < NEXP; e++) {
    float s = 0.f;
#pragma unroll
    for (int j = 0; j < 16; j++) s += xv[j] * rw[e * HID + j * 64 + l];
#pragma unroll
    for (int off = 32; off > 0; off >>= 1) s += __shfl_xor(s, off);
    p[e] = s;
  }
  float mx = p[0];
#pragma unroll
  for (int e = 1; e < NEXP; e++) mx = fmaxf(mx, p[e]);
  int idx[TOPK]; float w4[TOPK]; float wsum = 0.f; unsigned used = 0u;
#pragma unroll
  for (int k = 0; k < TOPK; k++) {
    float bv = -1e30f; int bi = 0;
#pragma unroll
    for (int e = 0; e < NEXP; e++)
      if (!((used >> e) & 1u) && p[e] > bv) { bv = p[e]; bi = e; }
    used |= 1u << bi;
    idx[k] = bi;
    w4[k] = __expf(p[bi] - mx);
    wsum += w4[k];
  }
  const float inv = 1.f / wsum;
  if (l < TOPK) {
    const int e = idx[l];
    const int pos = atomicAdd(&counts[e], 1);
    list[e * 1024 + pos] = t;
    wt[e * 1024 + pos]   = w4[l] * inv;
    tIdx[t * TOPK + l]   = (e << 10) | pos;
  }
}

// ---------------------------------------------------------------------------
// Phase 1: gate/up. Block 128m x 128j, 4 waves (wm=w>>1, wn=w&1), wave tile
// 64m x 64j = 4x4 frags, 16 MFMA/step, BK=32. A: glds16 2-buf (1 ahead).
// B: fp32 direct from Wg/Wu/Wsgu, reg-staged 2 ahead into fp32 LDS tile,
// transpose-read + pk2 to bf16. One barrier/step.
// z=0: shared. z>=1: routed expert z-1.
// ---------------------------------------------------------------------------
__global__ __launch_bounds__(256, 3) void phase1_kernel(
    const unsigned short* __restrict__ Xb,
    const float* __restrict__ Wg, const float* __restrict__ Wu,
    const float* __restrict__ Wsgu,
    const int* __restrict__ counts, const int* __restrict__ list,
    const float* __restrict__ wt,
    unsigned short* __restrict__ Hr,   // [16][4096][32]
    unsigned short* __restrict__ Hs) { // [32][1024][32]
  const int z = blockIdx.z, x = blockIdx.x, y = blockIdx.y;
  const bool routed = (z > 0);
  const int e = z - 1;
  int cnt = 0, base = 0;
  if (routed) {
    if (x >= 8) return;                // routed: 8 x-tiles of 128 packed cols
    cnt = counts[e];
    if (y * 128 >= cnt) return;
#pragma unroll
    for (int i = 0; i < NEXP; i++) base += (i < e) ? counts[i] : 0;
  }
  __shared__ __align__(16) unsigned short sA[2][128 * 32];
  __shared__ __align__(16) float sBF[2][32 * 132];
  const int tid = threadIdx.x, w = tid >> 6, l = tid & 63;
  const int wm = w >> 1, wn = w & 1, m0 = y * 128;
  const int swz = ((l & 3) ^ ((l >> 3) & 3)) * 8;

  // ---- A staging (bf16): wave w covers sA rows [32w,32w+32) as 2 glds
  const unsigned short* aS[2];
#pragma unroll
  for (int ii = 0; ii < 2; ii++) {
    const int r = 32 * w + 16 * ii + (l >> 2);
    const unsigned short* row = routed
        ? Xb + (size_t)list[e * 1024 + min(m0 + r, cnt - 1)] * HID
        : Xb + (size_t)(m0 + r) * HID;
    aS[ii] = row + swz;
  }

  // ---- B fp32 source: lane loads k-row 8w+(l>>3), G/U cols 64x+(l&7)*8..+8
  const int kRow = 8 * w + (l >> 3);
  const int cB = (l & 7) * 8;
  const float* gG0; const float* gU0; size_t bStepF;
  if (routed) {
    gG0 = Wg + ((size_t)e * HID + kRow) * MINTER + 64 * x + cB;
    gU0 = Wu + ((size_t)e * HID + kRow) * MINTER + 64 * x + cB;
    bStepF = (size_t)32 * MINTER;
  } else {
    gG0 = Wsgu + (size_t)kRow * 2048 + 64 * x + cB;
    gU0 = gG0 + 1024;
    bStepF = (size_t)32 * 2048;
  }
  // LDS fp32 tile write offsets: packed col J, XOR-swizzled by k>>3 (=w)
  const int Xw = (w & 3) << 4;
  const int JG = 32 * (cB >> 4) + (cB & 15);
  const int wG = kRow * 132 + (JG ^ Xw);
  const int wU = kRow * 132 + ((JG | 16) ^ Xw);

  // ---- LDS read offsets
  const int rsw = ((l >> 4) ^ (((l & 15) >> 1) & 3)) * 8;
  int aOff[4];
#pragma unroll
  for (int i = 0; i < 4; i++) aOff[i] = (64 * wm + 16 * i + (l & 15)) * 32 + rsw;
  int bBase[4];
#pragma unroll
  for (int jt = 0; jt < 4; jt++)
    bBase[jt] = (l >> 4) * (8 * 132) +
                ((64 * wn + 16 * jt + (l & 15)) ^ ((l >> 4) << 4));

  f32x4 acc[4][4];
#pragma unroll
  for (int i = 0; i < 4; i++)
#pragma unroll
    for (int jt = 0; jt < 4; jt++) acc[i][jt] = (f32x4){0.f, 0.f, 0.f, 0.f};

  float4 brA[4], brB[4];
  auto loadB = [&](int s, float4* br) {
    const float* g = gG0 + (size_t)s * bStepF;
    const float* u = gU0 + (size_t)s * bStepF;
    br[0] = *(const float4*)g; br[1] = *(const float4*)(g + 4);
    br[2] = *(const float4*)u; br[3] = *(const float4*)(u + 4);
  };
  auto storeB = [&](int b, const float4* br) {
    float* d = &sBF[b][0];
    *(float4*)(d + wG) = br[0]; *(float4*)(d + wG + 4) = br[1];
    *(float4*)(d + wU) = br[2]; *(float4*)(d + wU + 4) = br[3];
  };
  auto stageA = [&](int s, int b) {
    glds16(aS[0] + (size_t)s * 32, &sA[b][(32 * w) * 32]);
    glds16(aS[1] + (size_t)s * 32, &sA[b][(32 * w + 16) * 32]);
  };

  const int steps = HID / 32;   // 32
  // prologue: queue = [A0 x2, B0 x4, B1 x4]; vmcnt(4) drains A0,B0
  stageA(0, 0);
  loadB(0, brA);
  loadB(1, brB);
  WAIT_VM4();
  storeB(0, brA);
  BAR_LGKM();

  auto stepf = [&](int s, float4* brFill, float4* brSt) {
    const int cur = s & 1;
    if (s + 1 < steps) stageA(s + 1, cur ^ 1);
    if (s + 2 < steps) loadB(s + 2, brFill);
    const unsigned short* A = &sA[cur][0];
    const float* Bf = &sBF[cur][0];
    bf16x8 af[4];
#pragma unroll
    for (int i = 0; i < 4; i++) af[i] = as_bf16x8(*(const ushort8*)(A + aOff[i]));
#pragma unroll
    for (int jt = 0; jt < 4; jt++) {
      float f[8];
#pragma unroll
      for (int q = 0; q < 8; q++) f[q] = Bf[bBase[jt] + q * 132];
      union { uint32_t u[4]; bf16x8 v; } qq;
      qq.u[0] = pk2(f[1], f[0]); qq.u[1] = pk2(f[3], f[2]);
      qq.u[2] = pk2(f[5], f[4]); qq.u[3] = pk2(f[7], f[6]);
#pragma unroll
      for (int i = 0; i < 4; i++)
        acc[i][jt] = __builtin_amdgcn_mfma_f32_16x16x32_bf16(af[i], qq.v, acc[i][jt], 0, 0, 0);
    }
    if (s + 2 < steps) { WAIT_VM4(); } else { WAIT_VM0(); }
    if (s + 1 < steps) storeB((s + 1) & 1, brSt);
    BAR_LGKM();
  };
#pragma unroll 1
  for (int s = 0; s < steps; s += 2) {
    stepf(s, brA, brB);
    stepf(s + 1, brB, brA);
  }

  // epilogue: D col=lane&15, row=(lane>>4)*4+reg. jt pair (2p,2p+1) = (G,U)
  // for H panel (2x+wn), in-panel col 16p+(l&15).
  const int rl = (l >> 4) * 4, cl = l & 15;
  const int panel = 2 * x + wn;
#pragma unroll
  for (int i = 0; i < 4; i++)
#pragma unroll
    for (int r = 0; r < 4; r++) {
      const int grow = m0 + 64 * wm + 16 * i + rl + r;
#pragma unroll
      for (int p = 0; p < 2; p++) {
        const float g = acc[i][2 * p][r], u = acc[i][2 * p + 1][r];
        if (routed) {
          if (grow < cnt) {
            const float h = silu(g) * u * wt[e * 1024 + grow];
            Hr[((size_t)panel * 4096 + base + grow) * 32 + 16 * p + cl] = f2bf(h);
          }
        } else {
          const float h = silu(g) * u;
          Hs[((size_t)panel * 1024 + grow) * 32 + 16 * p + cl] = f2bf(h);
        }
      }
    }
}

// ---------------------------------------------------------------------------
// Phase 2: down-proj. Block 128m x 128n, same machinery. B = w_down/ws_down
// fp32 [K][H] (H fastest), lane loads one row-chunk of 16 floats.
// z=0: shared (K=1024 -> fp32 out). z>=1: routed (K=512 -> bf16 Rout).
// ---------------------------------------------------------------------------
__global__ __launch_bounds__(256, 3) void phase2_kernel(
    const unsigned short* __restrict__ Hr, const unsigned short* __restrict__ Hs,
    const float* __restrict__ Wd, const float* __restrict__ Wsd,
    const int* __restrict__ counts,
    unsigned short* __restrict__ Rout,   // bf16 [4096][1024]
    float* __restrict__ out) {           // fp32 [1024][1024]
  const int z = blockIdx.z, x = blockIdx.x, y = blockIdx.y;
  const bool routed = (z > 0);
  const int e = z - 1;
  int cnt = 0, base = 0, steps;
  if (routed) {
    cnt = counts[e];
    if (y * 128 >= cnt) return;
#pragma unroll
    for (int i = 0; i < NEXP; i++) base += (i < e) ? counts[i] : 0;
    steps = MINTER / 32;   // 16
  } else {
    steps = SINTER / 32;   // 32
  }
  __shared__ __align__(16) unsigned short sA[2][128 * 32];
  __shared__ __align__(16) float sBF[2][32 * 132];
  const int tid = threadIdx.x, w = tid >> 6, l = tid & 63;
  const int wm = w >> 1, wn = w & 1, m0 = y * 128;
  const int swz = ((l & 3) ^ ((l >> 3) & 3)) * 8;
  const size_t aStep = (size_t)(routed ? 4096 : 1024) * 32;

  const unsigned short* aS[2];
#pragma unroll
  for (int ii = 0; ii < 2; ii++) {
    const int r = 32 * w + 16 * ii + (l >> 2);
    const int R = routed ? (base + min(m0 + r, cnt - 1)) : (m0 + r);
    aS[ii] = (routed ? Hr : Hs) + (size_t)R * 32 + swz;
  }

  const int kRow = 8 * w + (l >> 3);
  const int cB = (l & 7) * 16;         // 16 floats per lane, one row
  const float* gB0 = routed
      ? Wd + ((size_t)e * MINTER + kRow) * HID + 128 * x + cB
      : Wsd + (size_t)kRow * HID + 128 * x + cB;
  const size_t bStepF = (size_t)32 * HID;

  const int Xw = (w & 3) << 4;
  const int wB = kRow * 132 + (cB ^ Xw);

  const int rsw = ((l >> 4) ^ (((l & 15) >> 1) & 3)) * 8;
  int aOff[4];
#pragma unroll
  for (int i = 0; i < 4; i++) aOff[i] = (64 * wm + 16 * i + (l & 15)) * 32 + rsw;
  int bBase[4];
#pragma unroll
  for (int jt = 0; jt < 4; jt++)
    bBase[jt] = (l >> 4) * (8 * 132) +
                ((64 * wn + 16 * jt + (l & 15)) ^ ((l >> 4) << 4));

  f32x4 acc[4][4];
#pragma unroll
  for (int i = 0; i < 4; i++)
#pragma unroll
    for (int jt = 0; jt < 4; jt++) acc[i][jt] = (f32x4){0.f, 0.f, 0.f, 0.f};

  float4 brA[4], brB[4];
  auto loadB = [&](int s, float4* br) {
    const float* g = gB0 + (size_t)s * bStepF;
    br[0] = *(const float4*)g;       br[1] = *(const float4*)(g + 4);
    br[2] = *(const float4*)(g + 8); br[3] = *(const float4*)(g + 12);
  };
  auto storeB = [&](int b, const float4* br) {
    float* d = &sBF[b][0];
    *(float4*)(d + wB) = br[0];     *(float4*)(d + wB + 4) = br[1];
    *(float4*)(d + wB + 8) = br[2]; *(float4*)(d + wB + 12) = br[3];
  };
  auto stageA = [&](int s, int b) {
    glds16(aS[0] + (size_t)s * aStep, &sA[b][(32 * w) * 32]);
    glds16(aS[1] + (size_t)s * aStep, &sA[b][(32 * w + 16) * 32]);
  };

  stageA(0, 0);
  loadB(0, brA);
  loadB(1, brB);
  WAIT_VM4();
  storeB(0, brA);
  BAR_LGKM();

  auto stepf = [&](int s, float4* brFill, float4* brSt) {
    const int cur = s & 1;
    if (s + 1 < steps) stageA(s + 1, cur ^ 1);
    if (s + 2 < steps) loadB(s + 2, brFill);
    const unsigned short* A = &sA[cur][0];
    const float* Bf = &sBF[cur][0];
    bf16x8 af[4];
#pragma unroll
    for (int i = 0; i < 4; i++) af[i] = as_bf16x8(*(const ushort8*)(A + aOff[i]));
#pragma unroll
    for (int jt = 0; jt < 4; jt++) {
      float f[8];
#pragma unroll
      for (int q = 0; q < 8; q++) f[q] = Bf[bBase[jt] + q * 132];
      union { uint32_t u[4]; bf16x8 v; } qq;
      qq.u[0] = pk2(f[1], f[0]); qq.u[1] = pk2(f[3], f[2]);
      qq.u[2] = pk2(f[5], f[4]); qq.u[3] = pk2(f[7], f[6]);
#pragma unroll
      for (int i = 0; i < 4; i++)
        acc[i][jt] = __builtin_amdgcn_mfma_f32_16x16x32_bf16(af[i], qq.v, acc[i][jt], 0, 0, 0);
    }
    if (s + 2 < steps) { WAIT_VM4(); } else { WAIT_VM0(); }
    if (s + 1 < steps) storeB((s + 1) & 1, brSt);
    BAR_LGKM();
  };
#pragma unroll 1
  for (int s = 0; s < steps; s += 2) {
    stepf(s, brA, brB);
    stepf(s + 1, brB, brA);
  }

  const int rl = (l >> 4) * 4, cl = l & 15;
#pragma unroll
  for (int i = 0; i < 4; i++)
#pragma unroll
    for (int r = 0; r < 4; r++) {
      const int grow = m0 + 64 * wm + 16 * i + rl + r;
#pragma unroll
      for (int jt = 0; jt < 4; jt++) {
        const int col = 128 * x + 64 * wn + 16 * jt + cl;
        if (routed) {
          if (grow < cnt)
            Rout[(size_t)(base + grow) * HID + col] = f2bf(acc[i][jt][r]);
        } else {
          out[(size_t)grow * HID + col] = acc[i][jt][r];
        }
      }
    }
}

// ------------- combine: out[t] += sum_k Rout[base[e_k]+pos_k] (bf16) -------
__global__ __launch_bounds__(256) void combine_kernel(
    const unsigned short* __restrict__ Rout, const int* __restrict__ counts,
    const int* __restrict__ tIdx, float* __restrict__ out) {
  __shared__ int sb[NEXP];
  if (threadIdx.x == 0) {
    int s = 0;
#pragma unroll
    for (int e = 0; e < NEXP; e++) { sb[e] = s; s += counts[e]; }
  }
  __syncthreads();
  const int t = blockIdx.x, c4 = threadIdx.x * 4;
  float4 o = *(const float4*)(out + (size_t)t * HID + c4);
#pragma unroll
  for (int k = 0; k < TOPK; k++) {
    const int v = tIdx[t * TOPK + k];
    const int row = sb[v >> 10] + (v & 1023);
    const uint2 rv = *(const uint2*)(Rout + (size_t)row * HID + c4);
    o.x += bfu2f(rv.x & 0xffffu); o.y += bfu2f(rv.x >> 16);
    o.z += bfu2f(rv.y & 0xffffu); o.w += bfu2f(rv.y >> 16);
  }
  *(float4*)(out + (size_t)t * HID + c4) = o;
}

// ---------------------------------------------------------------------------
extern "C" void kernel_launch(void* const* d_in, const int* in_sizes, int n_in,
                              void* d_out, int out_size, void* d_ws, size_t ws_size,
                              hipStream_t stream) {
  const float* x      = (const float*)d_in[0];
  const float* rw     = (const float*)d_in[1];
  const float* w_gate = (const float*)d_in[2];
  const float* w_up   = (const float*)d_in[3];
  const float* w_down = (const float*)d_in[4];
  const float* ws_gu  = (const float*)d_in[5];
  const float* ws_dn  = (const float*)d_in[6];
  float* out = (float*)d_out;
  char* ws = (char*)d_ws;

  int*   counts = (int*)  (ws + OFF_COUNTS);
  int*   list   = (int*)  (ws + OFF_LIST);
  float* wtbuf  = (float*)(ws + OFF_WT);
  int*   tIdx   = (int*)  (ws + OFF_TIDX);
  unsigned short* Xb   = (unsigned short*)(ws + OFF_XB);
  unsigned short* Hr   = (unsigned short*)(ws + OFF_HR);
  unsigned short* Hs   = (unsigned short*)(ws + OFF_HS);
  unsigned short* Rout = (unsigned short*)(ws + OFF_ROUT);

  init_kernel<<<1, 64, 0, stream>>>(counts);
  router_kernel<<<T_TOK, 64, 0, stream>>>(x, rw, counts, list, wtbuf, tIdx, Xb);
  phase1_kernel<<<dim3(16, 8, 17), 256, 0, stream>>>(
      Xb, w_gate, w_up, ws_gu, counts, list, wtbuf, Hr, Hs);
  phase2_kernel<<<dim3(8, 8, 17), 256, 0, stream>>>(
      Hr, Hs, w_down, ws_dn, counts, Rout, out);
  combine_kernel<<<T_TOK, 256, 0, stream>>>(Rout, counts, tIdx, out);
  (void)in_sizes; (void)n_in; (void)out_size; (void)ws_size;
}

// Round 4
// 278.957 us; speedup vs baseline: 1.4846x; 1.4846x over previous
//
#include <hip/hip_runtime.h>
#include <stdint.h>

// ---------------------------------------------------------------------------
// BailingMoE block: T=1024, H=1024, E=16, top-4, I=512 routed, Is=1024 shared
// R11: R10's fusion direction with its two bugs fixed via counter evidence:
//  (1) WRITE_SIZE 135MB = scratch from address-taken reg arrays -> B now
//      staged by global_load_lds (fp32, no register path at all).
//  (2) 5.2M LDS bank conflicts -> source pre-swizzle: odd waves XOR their
//      source cols by 16 floats; reads XOR by ((g&1)<<4) -> 2-way (free).
// B LDS tile [32][128] fp32 linear; transpose-read 32x ds_read_b32 + pk2
// to bf16 frags (named scalars, static indices). A path = R9's proven
// glds16 bf16. Pipeline = R9 skeleton: 3 buffers, vmcnt(6) counted barrier
// (6 loads/wave/stage = 2A + 4B). No pack kernel. LDS 72KB -> 2 blocks/CU.
// ---------------------------------------------------------------------------

typedef __attribute__((ext_vector_type(8))) unsigned short ushort8;
typedef __attribute__((ext_vector_type(4))) float f32x4;
typedef __attribute__((ext_vector_type(8))) __bf16 bf16x8;

#define T_TOK 1024
#define HID   1024
#define NEXP  16
#define TOPK  4
#define MINTER 512
#define SINTER 1024

constexpr size_t OFF_COUNTS = 0;
constexpr size_t OFF_LIST   = 1024;
constexpr size_t OFF_WT     = OFF_LIST  + 65536;
constexpr size_t OFF_TIDX   = OFF_WT    + 65536;
constexpr size_t OFF_XB     = OFF_TIDX  + 65536;               // bf16 [1024][1024]
constexpr size_t OFF_HR     = OFF_XB    + 2097152;             // bf16 [16][4096][32]
constexpr size_t OFF_HS     = OFF_HR    + 4194304;             // bf16 [32][1024][32]
constexpr size_t OFF_ROUT   = OFF_HS    + 2097152;             // bf16 [4096][1024]

__device__ __forceinline__ unsigned short f2bf(float f) {
  union { float f; uint32_t u; } v; v.f = f;
  uint32_t r = (v.u + 0x7FFFu + ((v.u >> 16) & 1u)) >> 16;
  return (unsigned short)r;
}
__device__ __forceinline__ float bfu2f(uint32_t u) {
  union { uint32_t u; float f; } v; v.u = u << 16; return v.f;
}
__device__ __forceinline__ bf16x8 as_bf16x8(ushort8 s) {
  union { ushort8 s; bf16x8 b; } u; u.s = s; return u.b;
}
// round-half-up fp32->bf16, two packed into one u32 (lo in low16)
__device__ __forceinline__ uint32_t pk2(float hi, float lo) {
  union { float f; uint32_t u; } a, b; a.f = hi; b.f = lo;
  return ((a.u + 0x8000u) & 0xFFFF0000u) | ((b.u + 0x8000u) >> 16);
}
__device__ __forceinline__ float silu(float g) { return g / (1.f + __expf(-g)); }

__device__ __forceinline__ void glds16(const void* g, void* l) {
  __builtin_amdgcn_global_load_lds(
      (const __attribute__((address_space(1))) unsigned int*)g,
      (__attribute__((address_space(3))) unsigned int*)l, 16, 0, 0);
}

// 6 glds/wave/stage (2 A + 4 B), 3 buffers. vmcnt(6) drains only the OLDEST
// stage (next stage's 6 loads stay in flight across the barrier). lgkmcnt(0):
// this wave's ds_reads of the previous step are in registers before any
// buffer can be overwritten.
#define PIPE_BARRIER6() asm volatile("s_waitcnt vmcnt(6) lgkmcnt(0)\ns_barrier" ::: "memory")
#define PIPE_BARRIER0() asm volatile("s_waitcnt vmcnt(0) lgkmcnt(0)\ns_barrier" ::: "memory")

// -------------------------- init: zero expert counts -----------------------
__global__ void init_kernel(int* counts) {
  if (threadIdx.x < NEXP) counts[threadIdx.x] = 0;
}

// ------------- router (fp32, one wave/token) + fused x->bf16 write ---------
__global__ __launch_bounds__(64) void router_kernel(
    const float* __restrict__ x, const float* __restrict__ rw,
    int* counts, int* list, float* wt, int* tIdx,
    unsigned short* __restrict__ Xb) {
  const int t = blockIdx.x, l = threadIdx.x;
  float xv[16];
#pragma unroll
  for (int j = 0; j < 16; j++) xv[j] = x[t * HID + j * 64 + l];
#pragma unroll
  for (int j = 0; j < 16; j++) Xb[t * HID + j * 64 + l] = f2bf(xv[j]);
  float p[NEXP];
#pragma unroll
  for (int e = 0; e < NEXP; e++) {
    float s = 0.f;
#pragma unroll
    for (int j = 0; j < 16; j++) s += xv[j] * rw[e * HID + j * 64 + l];
#pragma unroll
    for (int off = 32; off > 0; off >>= 1) s += __shfl_xor(s, off);
    p[e] = s;
  }
  float mx = p[0];
#pragma unroll
  for (int e = 1; e < NEXP; e++) mx = fmaxf(mx, p[e]);
  int idx[TOPK]; float w4[TOPK]; float wsum = 0.f; unsigned used = 0u;
#pragma unroll
  for (int k = 0; k < TOPK; k++) {
    float bv = -1e30f; int bi = 0;
#pragma unroll
    for (int e = 0; e < NEXP; e++)
      if (!((used >> e) & 1u) && p[e] > bv) { bv = p[e]; bi = e; }
    used |= 1u << bi;
    idx[k] = bi;
    w4[k] = __expf(p[bi] - mx);
    wsum += w4[k];
  }
  const float inv = 1.f / wsum;
  if (l < TOPK) {
    const int e = idx[l];
    const int pos = atomicAdd(&counts[e], 1);
    list[e * 1024 + pos] = t;
    wt[e * 1024 + pos]   = w4[l] * inv;
    tIdx[t * TOPK + l]   = (e << 10) | pos;
  }
}

// ---------------------------------------------------------------------------
// Phase 1: gate/up. Block 128m x 128j, 4 waves (wm=w>>1, wn=w&1), wave tile
// 64m x 64j = 4x4 frags (frag order: jt=2p+hf, hf 0=G 1=U), 16 MFMA/step,
// BK=32. A: glds16 bf16 [3][128*32]. B: glds16 fp32 [3][32][128]
// (cols 0-63 = G, 64-127 = U), odd waves pre-swizzle source cols ^16.
// z=0: shared. z>=1: routed expert z-1.
// ---------------------------------------------------------------------------
__global__ __launch_bounds__(256, 2) void phase1_kernel(
    const unsigned short* __restrict__ Xb,
    const float* __restrict__ Wg, const float* __restrict__ Wu,
    const float* __restrict__ Wsgu,
    const int* __restrict__ counts, const int* __restrict__ list,
    const float* __restrict__ wt,
    unsigned short* __restrict__ Hr,   // [16][4096][32]
    unsigned short* __restrict__ Hs) { // [32][1024][32]
  const int z = blockIdx.z, x = blockIdx.x, y = blockIdx.y;
  const bool routed = (z > 0);
  const int e = z - 1;
  int cnt = 0, base = 0;
  if (routed) {
    if (x >= 8) return;                // routed: 8 x-tiles of 64 I-cols
    cnt = counts[e];
    if (y * 128 >= cnt) return;
#pragma unroll
    for (int i = 0; i < NEXP; i++) base += (i < e) ? counts[i] : 0;
  }
  __shared__ __align__(16) unsigned short sA[3][128 * 32];
  __shared__ __align__(16) float sBF[3][32 * 128];
  const int tid = threadIdx.x, w = tid >> 6, l = tid & 63;
  const int wm = w >> 1, wn = w & 1, m0 = y * 128;
  const int g = l >> 4, r15 = l & 15;
  const int swz = ((l & 3) ^ ((l >> 3) & 3)) * 8;

  // ---- A staging (bf16): wave w covers sA rows [32w,32w+32) as 2 glds
  const unsigned short* aS[2];
#pragma unroll
  for (int ii = 0; ii < 2; ii++) {
    const int r = 32 * w + 16 * ii + (l >> 2);
    const unsigned short* row = routed
        ? Xb + (size_t)list[e * 1024 + min(m0 + r, cnt - 1)] * HID
        : Xb + (size_t)(m0 + r) * HID;
    aS[ii] = row + swz;
  }

  // ---- B staging (fp32 via glds16): wave w fills rows [8w, 8w+8).
  // glds i covers rows 8w+2i, 8w+2i+1; lane: row += (l>>5), lanes 0-15 = G
  // cols, 16-31 = U cols (4 floats each). Source col pre-swizzled ^16 for
  // odd waves (rows 8-15, 24-31) -> read-side XOR ((g&1)<<4) = 2-way banks.
  const int uHalf = (l & 31) >> 4;
  const int cg = (((l & 31) & 15) * 4) ^ ((w & 1) << 4);
  const float* bS[4];
  size_t bStepF;
#pragma unroll
  for (int i = 0; i < 4; i++) {
    const int r = 8 * w + 2 * i + (l >> 5);
    if (routed) {
      const float* mat = uHalf ? Wu : Wg;
      bS[i] = mat + ((size_t)e * HID + r) * MINTER + 64 * x + cg;
    } else {
      bS[i] = Wsgu + (size_t)r * 2048 + (size_t)uHalf * 1024 + 64 * x + cg;
    }
  }
  bStepF = routed ? (size_t)32 * MINTER : (size_t)32 * 2048;

  // ---- LDS read offsets
  const int rsw = (g ^ ((r15 >> 1) & 3)) * 8;
  int aOff[4];
#pragma unroll
  for (int i = 0; i < 4; i++) aOff[i] = (64 * wm + 16 * i + r15) * 32 + rsw;
  int bOff[4];
#pragma unroll
  for (int p = 0; p < 2; p++)
#pragma unroll
    for (int hf = 0; hf < 2; hf++)
      bOff[2 * p + hf] = 1024 * g + 64 * hf +
                         ((32 * wn + 16 * p + r15) ^ ((g & 1) << 4));

  f32x4 acc[4][4];
#pragma unroll
  for (int i = 0; i < 4; i++)
#pragma unroll
    for (int jt = 0; jt < 4; jt++) acc[i][jt] = (f32x4){0.f, 0.f, 0.f, 0.f};

  auto stage = [&](int s, int b) {
    glds16(aS[0] + (size_t)s * 32, &sA[b][(32 * w) * 32]);
    glds16(aS[1] + (size_t)s * 32, &sA[b][(32 * w + 16) * 32]);
    glds16(bS[0] + (size_t)s * bStepF, &sBF[b][(8 * w + 0) * 128]);
    glds16(bS[1] + (size_t)s * bStepF, &sBF[b][(8 * w + 2) * 128]);
    glds16(bS[2] + (size_t)s * bStepF, &sBF[b][(8 * w + 4) * 128]);
    glds16(bS[3] + (size_t)s * bStepF, &sBF[b][(8 * w + 6) * 128]);
  };

  const int steps = HID / 32;   // 32
  stage(0, 0); stage(1, 1);
#pragma unroll 1
  for (int s = 0; s < steps; s++) {
    const int cb = s % 3;
    if (s + 2 < steps)      { PIPE_BARRIER6(); stage(s + 2, (s + 2) % 3); }
    else if (s + 1 < steps) { PIPE_BARRIER6(); }
    else                    { PIPE_BARRIER0(); }
    const unsigned short* A = &sA[cb][0];
    const float* Bf = &sBF[cb][0];
    bf16x8 af[4];
#pragma unroll
    for (int i = 0; i < 4; i++) af[i] = as_bf16x8(*(const ushort8*)(A + aOff[i]));
#pragma unroll
    for (int jt = 0; jt < 4; jt++) {
      const float* src = Bf + bOff[jt];
      const float f0 = src[0 * 128], f1 = src[1 * 128];
      const float f2 = src[2 * 128], f3 = src[3 * 128];
      const float f4 = src[4 * 128], f5 = src[5 * 128];
      const float f6 = src[6 * 128], f7 = src[7 * 128];
      union { uint32_t u[4]; bf16x8 v; } qq;
      qq.u[0] = pk2(f1, f0); qq.u[1] = pk2(f3, f2);
      qq.u[2] = pk2(f5, f4); qq.u[3] = pk2(f7, f6);
#pragma unroll
      for (int i = 0; i < 4; i++)
        acc[i][jt] = __builtin_amdgcn_mfma_f32_16x16x32_bf16(af[i], qq.v, acc[i][jt], 0, 0, 0);
    }
  }

  // epilogue: D col=lane&15, row=(lane>>4)*4+reg. jt pair (2p,2p+1) = (G,U)
  // for H panel (2x+wn), in-panel col 16p+(l&15).
  const int rl = g * 4, cl = r15;
  const int panel = 2 * x + wn;
#pragma unroll
  for (int i = 0; i < 4; i++)
#pragma unroll
    for (int r = 0; r < 4; r++) {
      const int grow = m0 + 64 * wm + 16 * i + rl + r;
#pragma unroll
      for (int p = 0; p < 2; p++) {
        const float gv = acc[i][2 * p][r], uv = acc[i][2 * p + 1][r];
        if (routed) {
          if (grow < cnt) {
            const float h = silu(gv) * uv * wt[e * 1024 + grow];
            Hr[((size_t)panel * 4096 + base + grow) * 32 + 16 * p + cl] = f2bf(h);
          }
        } else {
          const float h = silu(gv) * uv;
          Hs[((size_t)panel * 1024 + grow) * 32 + 16 * p + cl] = f2bf(h);
        }
      }
    }
}

// ---------------------------------------------------------------------------
// Phase 2: down-proj. Block 128m x 128n, same machinery. B = w_down/ws_down
// fp32 [K][1024], tile [32][128] via glds16 with the same source pre-swizzle.
// z=0: shared (K=1024 -> fp32 out). z>=1: routed (K=512 -> bf16 Rout).
// ---------------------------------------------------------------------------
__global__ __launch_bounds__(256, 2) void phase2_kernel(
    const unsigned short* __restrict__ Hr, const unsigned short* __restrict__ Hs,
    const float* __restrict__ Wd, const float* __restrict__ Wsd,
    const int* __restrict__ counts,
    unsigned short* __restrict__ Rout,   // bf16 [4096][1024]
    float* __restrict__ out) {           // fp32 [1024][1024]
  const int z = blockIdx.z, x = blockIdx.x, y = blockIdx.y;
  const bool routed = (z > 0);
  const int e = z - 1;
  int cnt = 0, base = 0, steps;
  if (routed) {
    cnt = counts[e];
    if (y * 128 >= cnt) return;
#pragma unroll
    for (int i = 0; i < NEXP; i++) base += (i < e) ? counts[i] : 0;
    steps = MINTER / 32;   // 16
  } else {
    steps = SINTER / 32;   // 32
  }
  __shared__ __align__(16) unsigned short sA[3][128 * 32];
  __shared__ __align__(16) float sBF[3][32 * 128];
  const int tid = threadIdx.x, w = tid >> 6, l = tid & 63;
  const int wm = w >> 1, wn = w & 1, m0 = y * 128;
  const int g = l >> 4, r15 = l & 15;
  const int swz = ((l & 3) ^ ((l >> 3) & 3)) * 8;
  const size_t aStep = (size_t)(routed ? 4096 : 1024) * 32;

  const unsigned short* aS[2];
#pragma unroll
  for (int ii = 0; ii < 2; ii++) {
    const int r = 32 * w + 16 * ii + (l >> 2);
    const int R = routed ? (base + min(m0 + r, cnt - 1)) : (m0 + r);
    aS[ii] = (routed ? Hr : Hs) + (size_t)R * 32 + swz;
  }

  const int cg = ((l & 31) * 4) ^ ((w & 1) << 4);
  const float* bS[4];
#pragma unroll
  for (int i = 0; i < 4; i++) {
    const int r = 8 * w + 2 * i + (l >> 5);
    bS[i] = routed ? Wd + ((size_t)e * MINTER + r) * HID + 128 * x + cg
                   : Wsd + (size_t)r * HID + 128 * x + cg;
  }
  const size_t bStepF = (size_t)32 * HID;

  const int rsw = (g ^ ((r15 >> 1) & 3)) * 8;
  int aOff[4];
#pragma unroll
  for (int i = 0; i < 4; i++) aOff[i] = (64 * wm + 16 * i + r15) * 32 + rsw;
  int bOff[4];
#pragma unroll
  for (int jt = 0; jt < 4; jt++)
    bOff[jt] = 1024 * g + ((64 * wn + 16 * jt + r15) ^ ((g & 1) << 4));

  f32x4 acc[4][4];
#pragma unroll
  for (int i = 0; i < 4; i++)
#pragma unroll
    for (int jt = 0; jt < 4; jt++) acc[i][jt] = (f32x4){0.f, 0.f, 0.f, 0.f};

  auto stage = [&](int s, int b) {
    glds16(aS[0] + (size_t)s * aStep, &sA[b][(32 * w) * 32]);
    glds16(aS[1] + (size_t)s * aStep, &sA[b][(32 * w + 16) * 32]);
    glds16(bS[0] + (size_t)s * bStepF, &sBF[b][(8 * w + 0) * 128]);
    glds16(bS[1] + (size_t)s * bStepF, &sBF[b][(8 * w + 2) * 128]);
    glds16(bS[2] + (size_t)s * bStepF, &sBF[b][(8 * w + 4) * 128]);
    glds16(bS[3] + (size_t)s * bStepF, &sBF[b][(8 * w + 6) * 128]);
  };

  stage(0, 0); stage(1, 1);
#pragma unroll 1
  for (int s = 0; s < steps; s++) {
    const int cb = s % 3;
    if (s + 2 < steps)      { PIPE_BARRIER6(); stage(s + 2, (s + 2) % 3); }
    else if (s + 1 < steps) { PIPE_BARRIER6(); }
    else                    { PIPE_BARRIER0(); }
    const unsigned short* A = &sA[cb][0];
    const float* Bf = &sBF[cb][0];
    bf16x8 af[4];
#pragma unroll
    for (int i = 0; i < 4; i++) af[i] = as_bf16x8(*(const ushort8*)(A + aOff[i]));
#pragma unroll
    for (int jt = 0; jt < 4; jt++) {
      const float* src = Bf + bOff[jt];
      const float f0 = src[0 * 128], f1 = src[1 * 128];
      const float f2 = src[2 * 128], f3 = src[3 * 128];
      const float f4 = src[4 * 128], f5 = src[5 * 128];
      const float f6 = src[6 * 128], f7 = src[7 * 128];
      union { uint32_t u[4]; bf16x8 v; } qq;
      qq.u[0] = pk2(f1, f0); qq.u[1] = pk2(f3, f2);
      qq.u[2] = pk2(f5, f4); qq.u[3] = pk2(f7, f6);
#pragma unroll
      for (int i = 0; i < 4; i++)
        acc[i][jt] = __builtin_amdgcn_mfma_f32_16x16x32_bf16(af[i], qq.v, acc[i][jt], 0, 0, 0);
    }
  }

  const int rl = g * 4, cl = r15;
#pragma unroll
  for (int i = 0; i < 4; i++)
#pragma unroll
    for (int r = 0; r < 4; r++) {
      const int grow = m0 + 64 * wm + 16 * i + rl + r;
#pragma unroll
      for (int jt = 0; jt < 4; jt++) {
        const int col = 128 * x + 64 * wn + 16 * jt + cl;
        if (routed) {
          if (grow < cnt)
            Rout[(size_t)(base + grow) * HID + col] = f2bf(acc[i][jt][r]);
        } else {
          out[(size_t)grow * HID + col] = acc[i][jt][r];
        }
      }
    }
}

// ------------- combine: out[t] += sum_k Rout[base[e_k]+pos_k] (bf16) -------
__global__ __launch_bounds__(256) void combine_kernel(
    const unsigned short* __restrict__ Rout, const int* __restrict__ counts,
    const int* __restrict__ tIdx, float* __restrict__ out) {
  __shared__ int sb[NEXP];
  if (threadIdx.x == 0) {
    int s = 0;
#pragma unroll
    for (int e = 0; e < NEXP; e++) { sb[e] = s; s += counts[e]; }
  }
  __syncthreads();
  const int t = blockIdx.x, c4 = threadIdx.x * 4;
  float4 o = *(const float4*)(out + (size_t)t * HID + c4);
#pragma unroll
  for (int k = 0; k < TOPK; k++) {
    const int v = tIdx[t * TOPK + k];
    const int row = sb[v >> 10] + (v & 1023);
    const uint2 rv = *(const uint2*)(Rout + (size_t)row * HID + c4);
    o.x += bfu2f(rv.x & 0xffffu); o.y += bfu2f(rv.x >> 16);
    o.z += bfu2f(rv.y & 0xffffu); o.w += bfu2f(rv.y >> 16);
  }
  *(float4*)(out + (size_t)t * HID + c4) = o;
}

// ---------------------------------------------------------------------------
extern "C" void kernel_launch(void* const* d_in, const int* in_sizes, int n_in,
                              void* d_out, int out_size, void* d_ws, size_t ws_size,
                              hipStream_t stream) {
  const float* x      = (const float*)d_in[0];
  const float* rw     = (const float*)d_in[1];
  const float* w_gate = (const float*)d_in[2];
  const float* w_up   = (const float*)d_in[3];
  const float* w_down = (const float*)d_in[4];
  const float* ws_gu  = (const float*)d_in[5];
  const float* ws_dn  = (const float*)d_in[6];
  float* out = (float*)d_out;
  char* ws = (char*)d_ws;

  int*   counts = (int*)  (ws + OFF_COUNTS);
  int*   list   = (int*)  (ws + OFF_LIST);
  float* wtbuf  = (float*)(ws + OFF_WT);
  int*   tIdx   = (int*)  (ws + OFF_TIDX);
  unsigned short* Xb   = (unsigned short*)(ws + OFF_XB);
  unsigned short* Hr   = (unsigned short*)(ws + OFF_HR);
  unsigned short* Hs   = (unsigned short*)(ws + OFF_HS);
  unsigned short* Rout = (unsigned short*)(ws + OFF_ROUT);

  init_kernel<<<1, 64, 0, stream>>>(counts);
  router_kernel<<<T_TOK, 64, 0, stream>>>(x, rw, counts, list, wtbuf, tIdx, Xb);
  phase1_kernel<<<dim3(16, 8, 17), 256, 0, stream>>>(
      Xb, w_gate, w_up, ws_gu, counts, list, wtbuf, Hr, Hs);
  phase2_kernel<<<dim3(8, 8, 17), 256, 0, stream>>>(
      Hr, Hs, w_down, ws_dn, counts, Rout, out);
  combine_kernel<<<T_TOK, 256, 0, stream>>>(Rout, counts, tIdx, out);
  (void)in_sizes; (void)n_in; (void)out_size; (void)ws_size;
}